// Round 1
// baseline (1067.938 us; speedup 1.0000x reference)
//
#include <hip/hip_runtime.h>
#include <hip/hip_bf16.h>
#include <math.h>
#include <stdint.h>

typedef __attribute__((ext_vector_type(8))) short bf16x8_t;
typedef __attribute__((ext_vector_type(4))) float f32x4_t;

#define LOG2E 1.4426950408889634f

__device__ __forceinline__ unsigned short f2bf(float f) {
    union { float f; unsigned int u; } v; v.f = f;
    unsigned int r = v.u + 0x7FFFu + ((v.u >> 16) & 1u);
    return (unsigned short)(r >> 16);
}

// ---------------- elementwise cast fp32 -> bf16 ----------------
__global__ void cast_bf16_k(const float* __restrict__ in, unsigned short* __restrict__ out, int n4) {
    int i = blockIdx.x * blockDim.x + threadIdx.x;
    if (i < n4) {
        float4 v = ((const float4*)in)[i];
        ushort4 o;
        o.x = f2bf(v.x); o.y = f2bf(v.y); o.z = f2bf(v.z); o.w = f2bf(v.w);
        ((ushort4*)out)[i] = o;
    }
}

// ---------------- transpose + cast: W (K x N) fp32 -> Wt (N x K) bf16 ----------------
__global__ void transpose_cast_k(const float* __restrict__ W, unsigned short* __restrict__ Wt,
                                 int K, int N) {
    __shared__ float tile[32][33];
    int k0 = blockIdx.y * 32, n0 = blockIdx.x * 32;
    int tx = threadIdx.x, ty = threadIdx.y; // 32 x 8
#pragma unroll
    for (int i = 0; i < 32; i += 8)
        tile[ty + i][tx] = W[(long)(k0 + ty + i) * N + n0 + tx];
    __syncthreads();
#pragma unroll
    for (int i = 0; i < 32; i += 8)
        Wt[(long)(n0 + ty + i) * K + k0 + tx] = f2bf(tile[tx][ty + i]);
}

// ---------------- split heads: in [B*2048][1024] (col=d*16+h) -> out [B*16+h][2048][64] ----------------
__global__ __launch_bounds__(256) void split_heads_k(const unsigned short* __restrict__ in,
                                                     unsigned short* __restrict__ out) {
    __shared__ __align__(16) unsigned short t[16][1024];
    long l0 = (long)blockIdx.x * 16;
    int tid = threadIdx.x;
    for (int c = tid; c < 2048; c += 256) {
        int r = c >> 7, col = (c & 127) * 8;
        *(uint4*)(&t[r][col]) = *(const uint4*)(in + (l0 + r) * 1024 + col);
    }
    __syncthreads();
    int h = tid >> 4, lr = tid & 15;
    long l = l0 + lr;
    int b = (int)(l >> 11);
    int ll = (int)(l & 2047);
    unsigned short* op = out + ((long)(b * 16 + h) * 2048 + ll) * 64;
#pragma unroll
    for (int d8 = 0; d8 < 64; d8 += 8) {
        union { uint4 v; unsigned short s[8]; } u;
#pragma unroll
        for (int j = 0; j < 8; j++) u.s[j] = t[lr][(d8 + j) * 16 + h];
        *(uint4*)(op + d8) = u.v;
    }
}

// ---------------- GEMM: C(M,N) = A(M,K) @ Bt(N,K)^T, bf16 in, fp32 acc ----------------
// EP: 0 = fp32 out, 2 = bias+gelu -> bf16 out, 3 = bias -> fp32 out, 4 = bf16 out
template <int EP>
__global__ __launch_bounds__(256) void gemm_bt_k(const unsigned short* __restrict__ A,
                                                 const unsigned short* __restrict__ Bt,
                                                 void* __restrict__ outp,
                                                 const float* __restrict__ bias,
                                                 int M, int N, int K) {
    __shared__ __align__(16) unsigned short As[128 * 32];
    __shared__ __align__(16) unsigned short Bs[128 * 32];
    int tid = threadIdx.x;
    int wave = tid >> 6, lane = tid & 63;
    int wm = wave >> 1, wn = wave & 1;
    int quad = lane >> 4, l16 = lane & 15;
    int bm = blockIdx.y * 128, bn = blockIdx.x * 128;

    f32x4_t acc[4][4] = {};

    for (int k0 = 0; k0 < K; k0 += 32) {
        __syncthreads();
        for (int c = tid; c < 512; c += 256) {
            int row = c >> 2, col = (c & 3) * 8;
            *(uint4*)(As + row * 32 + col) = *(const uint4*)(A + (long)(bm + row) * K + k0 + col);
            *(uint4*)(Bs + row * 32 + col) = *(const uint4*)(Bt + (long)(bn + row) * K + k0 + col);
        }
        __syncthreads();
        bf16x8_t af[4], bfr[4];
#pragma unroll
        for (int t = 0; t < 4; t++) {
            af[t]  = *(const bf16x8_t*)(As + (wm * 64 + t * 16 + l16) * 32 + quad * 8);
            bfr[t] = *(const bf16x8_t*)(Bs + (wn * 64 + t * 16 + l16) * 32 + quad * 8);
        }
#pragma unroll
        for (int mt = 0; mt < 4; mt++)
#pragma unroll
            for (int nt = 0; nt < 4; nt++)
                acc[mt][nt] = __builtin_amdgcn_mfma_f32_16x16x32_bf16(af[mt], bfr[nt], acc[mt][nt], 0, 0, 0);
    }

#pragma unroll
    for (int mt = 0; mt < 4; mt++)
#pragma unroll
        for (int nt = 0; nt < 4; nt++)
#pragma unroll
            for (int r = 0; r < 4; r++) {
                int gm = bm + wm * 64 + mt * 16 + quad * 4 + r;
                int gn = bn + wn * 64 + nt * 16 + l16;
                float v = acc[mt][nt][r];
                if (EP == 0) {
                    ((float*)outp)[(long)gm * N + gn] = v;
                } else if (EP == 2) {
                    v += bias[gn];
                    v = 0.5f * v * (1.0f + erff(v * 0.70710678118654752f));
                    ((unsigned short*)outp)[(long)gm * N + gn] = f2bf(v);
                } else if (EP == 3) {
                    ((float*)outp)[(long)gm * N + gn] = v + bias[gn];
                } else {
                    ((unsigned short*)outp)[(long)gm * N + gn] = f2bf(v);
                }
            }
}

// ---------------- flash attention (value = K, per reference) ----------------
// Qh, Kh: [B*16+h][2048][64] bf16. out: [B*2048][1024] bf16 merged (col=d*16+h).
// mask applied BEFORE 1/8 scale, value -1e9. softmax over m.
__global__ __launch_bounds__(256) void flash_attn_k(const unsigned short* __restrict__ Qh,
                                                    const unsigned short* __restrict__ Kh,
                                                    const int* __restrict__ maskp,
                                                    unsigned short* __restrict__ out,
                                                    int use_mask) {
    __shared__ __align__(16) unsigned short Qs[128 * 64];
    __shared__ __align__(16) unsigned short K1[64 * 64]; // [m][d]
    __shared__ __align__(16) unsigned short K2[64 * 64]; // [d][m]
    __shared__ __align__(16) unsigned short Ps[128 * 64];
    __shared__ int ms[64];

    int tid = threadIdx.x;
    int wave = tid >> 6, lane = tid & 63;
    int quad = lane >> 4, l16 = lane & 15;
    int bh = blockIdx.y, b = bh >> 4, h = bh & 15;
    int l0 = blockIdx.x * 128;
    const unsigned short* Qbase = Qh + ((long)bh * 2048 + l0) * 64;
    const unsigned short* Kbase = Kh + (long)bh * 2048 * 64;

    for (int c = tid; c < 1024; c += 256) {
        int row = c >> 3, col = (c & 7) * 8;
        *(uint4*)(Qs + row * 64 + col) = *(const uint4*)(Qbase + row * 64 + col);
    }

    f32x4_t acc_o[2][4] = {};
    float m_run[2][4], l_run[2][4];
#pragma unroll
    for (int i = 0; i < 2; i++)
#pragma unroll
        for (int r = 0; r < 4; r++) { m_run[i][r] = -INFINITY; l_run[i][r] = 0.f; }

    for (int m0 = 0; m0 < 2048; m0 += 64) {
        __syncthreads();
        for (int c = tid; c < 512; c += 256) {
            int row = c >> 3, col = (c & 7) * 8;
            union { uint4 v; unsigned short s[8]; } u;
            u.v = *(const uint4*)(Kbase + (long)(m0 + row) * 64 + col);
            *(uint4*)(K1 + row * 64 + col) = u.v;
#pragma unroll
            for (int j = 0; j < 8; j++) K2[(col + j) * 64 + row] = u.s[j];
        }
        if (use_mask && tid < 64) ms[tid] = maskp[b * 2048 + m0 + tid];
        __syncthreads();

        // S = Q @ Ktile^T : per wave rows (l) = wave*32..+31, cols (m) = 0..63
        f32x4_t sacc[2][4] = {};
#pragma unroll
        for (int mt = 0; mt < 2; mt++)
#pragma unroll
            for (int kk = 0; kk < 2; kk++) {
                bf16x8_t af = *(const bf16x8_t*)(Qs + (wave * 32 + mt * 16 + l16) * 64 + kk * 32 + quad * 8);
#pragma unroll
                for (int nt = 0; nt < 4; nt++) {
                    bf16x8_t bfr = *(const bf16x8_t*)(K1 + (nt * 16 + l16) * 64 + kk * 32 + quad * 8);
                    sacc[mt][nt] = __builtin_amdgcn_mfma_f32_16x16x32_bf16(af, bfr, sacc[mt][nt], 0, 0, 0);
                }
            }

        // online softmax (rows fully within wave)
#pragma unroll
        for (int mt = 0; mt < 2; mt++)
#pragma unroll
            for (int r = 0; r < 4; r++) {
                float sv[4];
#pragma unroll
                for (int nt = 0; nt < 4; nt++) {
                    float s = sacc[mt][nt][r];
                    if (use_mask && ms[nt * 16 + l16]) s = -1e9f;
                    sv[nt] = s * 0.125f;
                }
                float mx = fmaxf(fmaxf(sv[0], sv[1]), fmaxf(sv[2], sv[3]));
#pragma unroll
                for (int d = 1; d < 16; d <<= 1) mx = fmaxf(mx, __shfl_xor(mx, d));
                float mnew = fmaxf(m_run[mt][r], mx);
                float alpha = exp2f((m_run[mt][r] - mnew) * LOG2E);
                float pv[4], psum = 0.f;
#pragma unroll
                for (int nt = 0; nt < 4; nt++) { pv[nt] = exp2f((sv[nt] - mnew) * LOG2E); psum += pv[nt]; }
#pragma unroll
                for (int d = 1; d < 16; d <<= 1) psum += __shfl_xor(psum, d);
                l_run[mt][r] = l_run[mt][r] * alpha + psum;
                m_run[mt][r] = mnew;
#pragma unroll
                for (int nt = 0; nt < 4; nt++) {
                    acc_o[mt][nt][r] *= alpha;
                    Ps[(wave * 32 + mt * 16 + quad * 4 + r) * 64 + nt * 16 + l16] = f2bf(pv[nt]);
                }
            }

        // O += P @ Ktile  (A = Ps rows of this wave, B via K2 [d][m])
#pragma unroll
        for (int mt = 0; mt < 2; mt++)
#pragma unroll
            for (int kk = 0; kk < 2; kk++) {
                bf16x8_t af = *(const bf16x8_t*)(Ps + (wave * 32 + mt * 16 + l16) * 64 + kk * 32 + quad * 8);
#pragma unroll
                for (int nt = 0; nt < 4; nt++) {
                    bf16x8_t bfr = *(const bf16x8_t*)(K2 + (nt * 16 + l16) * 64 + kk * 32 + quad * 8);
                    acc_o[mt][nt] = __builtin_amdgcn_mfma_f32_16x16x32_bf16(af, bfr, acc_o[mt][nt], 0, 0, 0);
                }
            }
    }

#pragma unroll
    for (int mt = 0; mt < 2; mt++)
#pragma unroll
        for (int r = 0; r < 4; r++) {
            float inv = 1.0f / l_run[mt][r];
            int l = l0 + wave * 32 + mt * 16 + quad * 4 + r;
#pragma unroll
            for (int nt = 0; nt < 4; nt++) {
                int d = nt * 16 + l16;
                out[((long)(b * 2048 + l)) * 1024 + d * 16 + h] = f2bf(acc_o[mt][nt][r] * inv);
            }
        }
}

// ---------------- residual + layernorm: out = LN(a + rb) * g + b ----------------
__global__ __launch_bounds__(256) void resid_ln_k(const float* __restrict__ a,
                                                  const float* __restrict__ rb,
                                                  const float* __restrict__ g,
                                                  const float* __restrict__ bb,
                                                  float* __restrict__ outf,
                                                  unsigned short* __restrict__ outb) {
    long row = blockIdx.x;
    int tid = threadIdx.x;
    float4 va = ((const float4*)(a + row * 1024))[tid];
    float4 vr = ((const float4*)(rb + row * 1024))[tid];
    float x0 = va.x + vr.x, x1 = va.y + vr.y, x2 = va.z + vr.z, x3 = va.w + vr.w;
    float s = x0 + x1 + x2 + x3;
    float sq = x0 * x0 + x1 * x1 + x2 * x2 + x3 * x3;
#pragma unroll
    for (int d = 1; d < 64; d <<= 1) { s += __shfl_xor(s, d); sq += __shfl_xor(sq, d); }
    __shared__ float ss[4], ssq[4];
    int wave = tid >> 6, lane = tid & 63;
    if (lane == 0) { ss[wave] = s; ssq[wave] = sq; }
    __syncthreads();
    s = ss[0] + ss[1] + ss[2] + ss[3];
    sq = ssq[0] + ssq[1] + ssq[2] + ssq[3];
    float mean = s * (1.0f / 1024.0f);
    float var = sq * (1.0f / 1024.0f) - mean * mean;
    float rstd = rsqrtf(var + 1e-5f);
    float4 vg = ((const float4*)g)[tid];
    float4 vb = ((const float4*)bb)[tid];
    float y0 = (x0 - mean) * rstd * vg.x + vb.x;
    float y1 = (x1 - mean) * rstd * vg.y + vb.y;
    float y2 = (x2 - mean) * rstd * vg.z + vb.z;
    float y3 = (x3 - mean) * rstd * vg.w + vb.w;
    float4 o; o.x = y0; o.y = y1; o.z = y2; o.w = y3;
    ((float4*)(outf + row * 1024))[tid] = o;
    ushort4 ob; ob.x = f2bf(y0); ob.y = f2bf(y1); ob.z = f2bf(y2); ob.w = f2bf(y3);
    ((ushort4*)(outb + row * 1024))[tid] = ob;
}

extern "C" void kernel_launch(void* const* d_in, const int* in_sizes, int n_in,
                              void* d_out, int out_size, void* d_ws, size_t ws_size,
                              hipStream_t stream) {
    const float* x    = (const float*)d_in[0];
    const float* enc  = (const float*)d_in[1];
    const int*   mask = (const int*)d_in[2];
    const float* q1W  = (const float*)d_in[3];
    const float* w1W  = (const float*)d_in[4];
    const float* o1W  = (const float*)d_in[5];
    const float* q2W  = (const float*)d_in[6];
    const float* w2W  = (const float*)d_in[7];
    const float* o2W  = (const float*)d_in[8];
    const float* ffW1 = (const float*)d_in[9];
    const float* ffb1 = (const float*)d_in[10];
    const float* ffW2 = (const float*)d_in[11];
    const float* ffb2 = (const float*)d_in[12];
    const float* g1 = (const float*)d_in[13];
    const float* b1 = (const float*)d_in[14];
    const float* g2 = (const float*)d_in[15];
    const float* b2 = (const float*)d_in[16];
    const float* g3 = (const float*)d_in[17];
    const float* b3 = (const float*)d_in[18];
    float* outp = (float*)d_out;

    const int T = 4096;   // B*L
    const int D = 1024;
    const int F = 4096;   // MLP

    char* ws = (char*)d_ws;
    auto alloc = [&](size_t sz) { char* p = ws; ws += (sz + 255) & ~(size_t)255; return p; };
    unsigned short* q1Wt  = (unsigned short*)alloc((size_t)D * D * 2);
    unsigned short* w1Wt  = (unsigned short*)alloc((size_t)D * D * 2);
    unsigned short* o1Wt  = (unsigned short*)alloc((size_t)D * D * 2);
    unsigned short* q2Wt  = (unsigned short*)alloc((size_t)D * D * 2);
    unsigned short* w2Wt  = (unsigned short*)alloc((size_t)D * D * 2);
    unsigned short* o2Wt  = (unsigned short*)alloc((size_t)D * D * 2);
    unsigned short* ffW1t = (unsigned short*)alloc((size_t)F * D * 2);
    unsigned short* ffW2t = (unsigned short*)alloc((size_t)D * F * 2);
    unsigned short* xb    = (unsigned short*)alloc((size_t)T * D * 2);
    unsigned short* encb  = (unsigned short*)alloc((size_t)T * D * 2);
    unsigned short* tmpb  = (unsigned short*)alloc((size_t)T * D * 2);
    unsigned short* Qhb   = (unsigned short*)alloc((size_t)T * D * 2);
    unsigned short* Khb   = (unsigned short*)alloc((size_t)T * D * 2);
    unsigned short* attnb = (unsigned short*)alloc((size_t)T * D * 2);
    float*          projf = (float*)alloc((size_t)T * D * 4);
    float*          x1f   = (float*)alloc((size_t)T * D * 4);
    unsigned short* x1b   = (unsigned short*)alloc((size_t)T * D * 2);
    float*          x2f   = (float*)alloc((size_t)T * D * 4);
    unsigned short* x2b   = (unsigned short*)alloc((size_t)T * D * 2);
    unsigned short* hb    = (unsigned short*)alloc((size_t)T * F * 2);

    dim3 blk256(256);
    dim3 tblk(32, 8);

    // casts
    cast_bf16_k<<<dim3((T * D / 4 + 255) / 256), blk256, 0, stream>>>(x, xb, T * D / 4);
    cast_bf16_k<<<dim3((T * D / 4 + 255) / 256), blk256, 0, stream>>>(enc, encb, T * D / 4);
    transpose_cast_k<<<dim3(D / 32, D / 32), tblk, 0, stream>>>(q1W, q1Wt, D, D);
    transpose_cast_k<<<dim3(D / 32, D / 32), tblk, 0, stream>>>(w1W, w1Wt, D, D);
    transpose_cast_k<<<dim3(D / 32, D / 32), tblk, 0, stream>>>(o1W, o1Wt, D, D);
    transpose_cast_k<<<dim3(D / 32, D / 32), tblk, 0, stream>>>(q2W, q2Wt, D, D);
    transpose_cast_k<<<dim3(D / 32, D / 32), tblk, 0, stream>>>(w2W, w2Wt, D, D);
    transpose_cast_k<<<dim3(D / 32, D / 32), tblk, 0, stream>>>(o2W, o2Wt, D, D);
    transpose_cast_k<<<dim3(F / 32, D / 32), tblk, 0, stream>>>(ffW1, ffW1t, D, F);
    transpose_cast_k<<<dim3(D / 32, F / 32), tblk, 0, stream>>>(ffW2, ffW2t, F, D);

    // ---- self attention ----
    gemm_bt_k<4><<<dim3(D / 128, T / 128), blk256, 0, stream>>>(xb, q1Wt, tmpb, nullptr, T, D, D);
    split_heads_k<<<dim3(T / 16), blk256, 0, stream>>>(tmpb, Qhb);
    gemm_bt_k<4><<<dim3(D / 128, T / 128), blk256, 0, stream>>>(xb, w1Wt, tmpb, nullptr, T, D, D);
    split_heads_k<<<dim3(T / 16), blk256, 0, stream>>>(tmpb, Khb);
    flash_attn_k<<<dim3(16, 32), blk256, 0, stream>>>(Qhb, Khb, nullptr, attnb, 0);
    gemm_bt_k<0><<<dim3(D / 128, T / 128), blk256, 0, stream>>>(attnb, o1Wt, projf, nullptr, T, D, D);
    resid_ln_k<<<dim3(T), blk256, 0, stream>>>(x, projf, g1, b1, x1f, x1b);

    // ---- cross attention ----
    gemm_bt_k<4><<<dim3(D / 128, T / 128), blk256, 0, stream>>>(x1b, q2Wt, tmpb, nullptr, T, D, D);
    split_heads_k<<<dim3(T / 16), blk256, 0, stream>>>(tmpb, Qhb);
    gemm_bt_k<4><<<dim3(D / 128, T / 128), blk256, 0, stream>>>(encb, w2Wt, tmpb, nullptr, T, D, D);
    split_heads_k<<<dim3(T / 16), blk256, 0, stream>>>(tmpb, Khb);
    flash_attn_k<<<dim3(16, 32), blk256, 0, stream>>>(Qhb, Khb, mask, attnb, 1);
    gemm_bt_k<0><<<dim3(D / 128, T / 128), blk256, 0, stream>>>(attnb, o2Wt, projf, nullptr, T, D, D);
    resid_ln_k<<<dim3(T), blk256, 0, stream>>>(x1f, projf, g2, b2, x2f, x2b);

    // ---- feed forward ----
    gemm_bt_k<2><<<dim3(F / 128, T / 128), blk256, 0, stream>>>(x2b, ffW1t, hb, ffb1, T, F, D);
    gemm_bt_k<3><<<dim3(D / 128, T / 128), blk256, 0, stream>>>(hb, ffW2t, projf, ffb2, T, D, F);
    resid_ln_k<<<dim3(T), blk256, 0, stream>>>(x2f, projf, g3, b3, outp, xb);
}

// Round 2
// 840.636 us; speedup vs baseline: 1.2704x; 1.2704x over previous
//
#include <hip/hip_runtime.h>
#include <hip/hip_bf16.h>
#include <math.h>
#include <stdint.h>

typedef __attribute__((ext_vector_type(8))) short bf16x8_t;
typedef __attribute__((ext_vector_type(4))) float f32x4_t;

#define LOG2E 1.4426950408889634f
#define GLB(p) ((const __attribute__((address_space(1))) void*)(p))
#define LDS(p) ((__attribute__((address_space(3))) void*)(p))

__device__ __forceinline__ unsigned short f2bf(float f) {
    union { float f; unsigned int u; } v; v.f = f;
    unsigned int r = v.u + 0x7FFFu + ((v.u >> 16) & 1u);
    return (unsigned short)(r >> 16);
}

// ---------------- elementwise cast fp32 -> bf16 ----------------
__global__ void cast_bf16_k(const float* __restrict__ in, unsigned short* __restrict__ out, int n4) {
    int i = blockIdx.x * blockDim.x + threadIdx.x;
    if (i < n4) {
        float4 v = ((const float4*)in)[i];
        ushort4 o;
        o.x = f2bf(v.x); o.y = f2bf(v.y); o.z = f2bf(v.z); o.w = f2bf(v.w);
        ((ushort4*)out)[i] = o;
    }
}

// ---------------- transpose + cast: W (K x N) fp32 -> Wt (N x K) bf16 ----------------
__global__ void transpose_cast_k(const float* __restrict__ W, unsigned short* __restrict__ Wt,
                                 int K, int N) {
    __shared__ float tile[32][33];
    int k0 = blockIdx.y * 32, n0 = blockIdx.x * 32;
    int tx = threadIdx.x, ty = threadIdx.y; // 32 x 8
#pragma unroll
    for (int i = 0; i < 32; i += 8)
        tile[ty + i][tx] = W[(long)(k0 + ty + i) * N + n0 + tx];
    __syncthreads();
#pragma unroll
    for (int i = 0; i < 32; i += 8)
        Wt[(long)(n0 + ty + i) * K + k0 + tx] = f2bf(tile[tx][ty + i]);
}

// ---------------- split heads: in [4096][stride] (col=coloff + d*16+h) -> out [B*16+h][2048][64] ----------------
__global__ __launch_bounds__(256) void split_heads_k(const unsigned short* __restrict__ in,
                                                     unsigned short* __restrict__ out,
                                                     int stride, int coloff) {
    __shared__ __align__(16) unsigned short t[16][1024];
    long l0 = (long)blockIdx.x * 16;
    int tid = threadIdx.x;
    for (int c = tid; c < 2048; c += 256) {
        int r = c >> 7, col = (c & 127) * 8;
        *(uint4*)(&t[r][col]) = *(const uint4*)(in + (l0 + r) * stride + coloff + col);
    }
    __syncthreads();
    int h = tid >> 4, lr = tid & 15;
    long l = l0 + lr;
    int b = (int)(l >> 11);
    int ll = (int)(l & 2047);
    unsigned short* op = out + ((long)(b * 16 + h) * 2048 + ll) * 64;
#pragma unroll
    for (int d8 = 0; d8 < 64; d8 += 8) {
        union { uint4 v; unsigned short s[8]; } u;
#pragma unroll
        for (int j = 0; j < 8; j++) u.s[j] = t[lr][(d8 + j) * 16 + h];
        *(uint4*)(op + d8) = u.v;
    }
}

// ---------------- per-head transpose: Kh [bh][2048][64] -> KhT [bh][64][2048] ----------------
__global__ __launch_bounds__(256) void transpose_heads_k(const unsigned short* __restrict__ in,
                                                         unsigned short* __restrict__ out) {
    __shared__ unsigned short t[64][72];
    int bh = blockIdx.y;
    int m0 = blockIdx.x * 64;
    int tid = threadIdx.x;
    for (int c = tid; c < 512; c += 256) {
        int r = c >> 3, col = (c & 7) * 8;
        *(uint4*)(&t[r][col]) = *(const uint4*)(in + ((long)bh * 2048 + m0 + r) * 64 + col);
    }
    __syncthreads();
    for (int c = tid; c < 512; c += 256) {
        int d = c >> 3, mc = (c & 7) * 8;
        union { uint4 v; unsigned short s[8]; } u;
#pragma unroll
        for (int j = 0; j < 8; j++) u.s[j] = t[mc + j][d];
        *(uint4*)(out + ((long)bh * 64 + d) * 2048 + m0 + mc) = u.v;
    }
}

// ---------------- GEMM: C(M,N) = A(M,K) @ Bt(N,K)^T, bf16 in, fp32 acc ----------------
// m97 structure: global_load_lds width-16 staging, 128x128 tile, BK=32.
// EP: 0 = fp32 out, 2 = bias+gelu -> bf16 out, 3 = bias -> fp32 out, 4 = bf16 out
template <int EP>
__global__ __launch_bounds__(256) void gemm_bt2_k(const unsigned short* __restrict__ A,
                                                  const unsigned short* __restrict__ Bt,
                                                  void* __restrict__ outp,
                                                  const float* __restrict__ bias,
                                                  int M, int N, int K) {
    __shared__ __align__(16) unsigned short As[128 * 32];
    __shared__ __align__(16) unsigned short Bs[128 * 32];
    int tid = threadIdx.x;
    int wave = tid >> 6, lane = tid & 63;
    int wm = wave >> 1, wn = wave & 1;
    int quad = lane >> 4, l16 = lane & 15;
    int bm = blockIdx.y * 128, bn = blockIdx.x * 128;

    f32x4_t acc[4][4] = {};

    const unsigned short* Ag0 = A + (long)(bm + (tid >> 2)) * K + (tid & 3) * 8;
    const unsigned short* Ag1 = A + (long)(bm + (tid >> 2) + 64) * K + (tid & 3) * 8;
    const unsigned short* Bg0 = Bt + (long)(bn + (tid >> 2)) * K + (tid & 3) * 8;
    const unsigned short* Bg1 = Bt + (long)(bn + (tid >> 2) + 64) * K + (tid & 3) * 8;
    unsigned short* Al0 = As + tid * 8;
    unsigned short* Al1 = As + tid * 8 + 2048;
    unsigned short* Bl0 = Bs + tid * 8;
    unsigned short* Bl1 = Bs + tid * 8 + 2048;

    for (int k0 = 0; k0 < K; k0 += 32) {
        __syncthreads();
        __builtin_amdgcn_global_load_lds(GLB(Ag0 + k0), LDS(Al0), 16, 0, 0);
        __builtin_amdgcn_global_load_lds(GLB(Ag1 + k0), LDS(Al1), 16, 0, 0);
        __builtin_amdgcn_global_load_lds(GLB(Bg0 + k0), LDS(Bl0), 16, 0, 0);
        __builtin_amdgcn_global_load_lds(GLB(Bg1 + k0), LDS(Bl1), 16, 0, 0);
        __syncthreads();
        bf16x8_t af[4], bfr[4];
#pragma unroll
        for (int t = 0; t < 4; t++) {
            af[t]  = *(const bf16x8_t*)(As + (wm * 64 + t * 16 + l16) * 32 + quad * 8);
            bfr[t] = *(const bf16x8_t*)(Bs + (wn * 64 + t * 16 + l16) * 32 + quad * 8);
        }
#pragma unroll
        for (int mt = 0; mt < 4; mt++)
#pragma unroll
            for (int nt = 0; nt < 4; nt++)
                acc[mt][nt] = __builtin_amdgcn_mfma_f32_16x16x32_bf16(af[mt], bfr[nt], acc[mt][nt], 0, 0, 0);
    }

#pragma unroll
    for (int mt = 0; mt < 4; mt++)
#pragma unroll
        for (int nt = 0; nt < 4; nt++)
#pragma unroll
            for (int r = 0; r < 4; r++) {
                int gm = bm + wm * 64 + mt * 16 + quad * 4 + r;
                int gn = bn + wn * 64 + nt * 16 + l16;
                float v = acc[mt][nt][r];
                if (EP == 0) {
                    ((float*)outp)[(long)gm * N + gn] = v;
                } else if (EP == 2) {
                    v += bias[gn];
                    v = 0.5f * v * (1.0f + erff(v * 0.70710678118654752f));
                    ((unsigned short*)outp)[(long)gm * N + gn] = f2bf(v);
                } else if (EP == 3) {
                    ((float*)outp)[(long)gm * N + gn] = v + bias[gn];
                } else {
                    ((unsigned short*)outp)[(long)gm * N + gn] = f2bf(v);
                }
            }
}

// ---------------- flash attention v2 (value = K, per reference) ----------------
// Qh, Kh: [bh][2048][64]; KhT: [bh][64][2048]. out: [4096][1024] bf16 (col=d*16+h).
// Q tile 64 rows (16 per wave), K tile 64. All LDS strides padded to 72 shorts.
__global__ __launch_bounds__(256) void flash_attn2_k(const unsigned short* __restrict__ Qh,
                                                     const unsigned short* __restrict__ Kh,
                                                     const unsigned short* __restrict__ KhT,
                                                     const int* __restrict__ maskp,
                                                     unsigned short* __restrict__ out,
                                                     int use_mask) {
    __shared__ __align__(16) unsigned short Qs[64 * 72];
    __shared__ __align__(16) unsigned short K1[64 * 72]; // [m][d]
    __shared__ __align__(16) unsigned short K2[64 * 72]; // [d][m]
    __shared__ __align__(16) unsigned short Ps[64 * 72];
    __shared__ int ms[64];

    int tid = threadIdx.x;
    int wave = tid >> 6, lane = tid & 63;
    int quad = lane >> 4, l16 = lane & 15;
    int bh = blockIdx.y, b = bh >> 4, h = bh & 15;
    int l0 = blockIdx.x * 64;
    const unsigned short* Qbase = Qh + ((long)bh * 2048 + l0) * 64;
    const unsigned short* Kbase = Kh + (long)bh * 2048 * 64;
    const unsigned short* KTbase = KhT + (long)bh * 64 * 2048;

    for (int c = tid; c < 512; c += 256) {
        int row = c >> 3, col = (c & 7) * 8;
        *(uint4*)(Qs + row * 72 + col) = *(const uint4*)(Qbase + row * 64 + col);
    }

    f32x4_t acc_o[4] = {};
    float m_run[4], l_run[4];
#pragma unroll
    for (int r = 0; r < 4; r++) { m_run[r] = -INFINITY; l_run[r] = 0.f; }

    int row_s = tid >> 3, col_s = (tid & 7) * 8; // staging coords (256 threads -> 2 chunks each)

    for (int m0 = 0; m0 < 2048; m0 += 64) {
        __syncthreads();
        for (int c = tid; c < 512; c += 256) {
            int row = c >> 3, col = (c & 7) * 8;
            *(uint4*)(K1 + row * 72 + col) = *(const uint4*)(Kbase + (long)(m0 + row) * 64 + col);
            *(uint4*)(K2 + row * 72 + col) = *(const uint4*)(KTbase + (long)row * 2048 + m0 + col);
        }
        if (use_mask && tid < 64) ms[tid] = maskp[b * 2048 + m0 + tid];
        __syncthreads();

        // S = Q @ Ktile^T : wave handles 16 Q rows (band = wave*16), 64 m cols
        f32x4_t sacc[4] = {};
#pragma unroll
        for (int kk = 0; kk < 2; kk++) {
            bf16x8_t af = *(const bf16x8_t*)(Qs + (wave * 16 + l16) * 72 + kk * 32 + quad * 8);
#pragma unroll
            for (int nt = 0; nt < 4; nt++) {
                bf16x8_t bfr = *(const bf16x8_t*)(K1 + (nt * 16 + l16) * 72 + kk * 32 + quad * 8);
                sacc[nt] = __builtin_amdgcn_mfma_f32_16x16x32_bf16(af, bfr, sacc[nt], 0, 0, 0);
            }
        }

        // online softmax: row l = quad*4 + r (within band), reduce over nt (in-lane) and l16 (shfl)
#pragma unroll
        for (int r = 0; r < 4; r++) {
            float sv[4];
#pragma unroll
            for (int nt = 0; nt < 4; nt++) {
                float s = sacc[nt][r];
                if (use_mask && ms[nt * 16 + l16]) s = -1e9f;
                sv[nt] = s * 0.125f;
            }
            float mx = fmaxf(fmaxf(sv[0], sv[1]), fmaxf(sv[2], sv[3]));
#pragma unroll
            for (int d = 1; d < 16; d <<= 1) mx = fmaxf(mx, __shfl_xor(mx, d));
            float mnew = fmaxf(m_run[r], mx);
            float alpha = exp2f((m_run[r] - mnew) * LOG2E);
            float pv[4], psum = 0.f;
#pragma unroll
            for (int nt = 0; nt < 4; nt++) { pv[nt] = exp2f((sv[nt] - mnew) * LOG2E); psum += pv[nt]; }
#pragma unroll
            for (int d = 1; d < 16; d <<= 1) psum += __shfl_xor(psum, d);
            l_run[r] = l_run[r] * alpha + psum;
            m_run[r] = mnew;
#pragma unroll
            for (int nt = 0; nt < 4; nt++) {
                acc_o[nt][r] *= alpha;
                Ps[(wave * 16 + quad * 4 + r) * 72 + nt * 16 + l16] = f2bf(pv[nt]);
            }
        }

        // O += P @ Ktile : A = own band of Ps, B = K2 [d][m]
#pragma unroll
        for (int kk = 0; kk < 2; kk++) {
            bf16x8_t af = *(const bf16x8_t*)(Ps + (wave * 16 + l16) * 72 + kk * 32 + quad * 8);
#pragma unroll
            for (int nt = 0; nt < 4; nt++) {
                bf16x8_t bfr = *(const bf16x8_t*)(K2 + (nt * 16 + l16) * 72 + kk * 32 + quad * 8);
                acc_o[nt] = __builtin_amdgcn_mfma_f32_16x16x32_bf16(af, bfr, acc_o[nt], 0, 0, 0);
            }
        }
    }

#pragma unroll
    for (int r = 0; r < 4; r++) {
        float inv = 1.0f / l_run[r];
        int l = l0 + wave * 16 + quad * 4 + r;
#pragma unroll
        for (int nt = 0; nt < 4; nt++) {
            int d = nt * 16 + l16;
            out[((long)(b * 2048 + l)) * 1024 + d * 16 + h] = f2bf(acc_o[nt][r] * inv);
        }
    }
    (void)row_s; (void)col_s;
}

// ---------------- residual + layernorm: out = LN(a + rb) * g + b ----------------
__global__ __launch_bounds__(256) void resid_ln_k(const float* __restrict__ a,
                                                  const float* __restrict__ rb,
                                                  const float* __restrict__ g,
                                                  const float* __restrict__ bb,
                                                  float* __restrict__ outf,
                                                  unsigned short* __restrict__ outb) {
    long row = blockIdx.x;
    int tid = threadIdx.x;
    float4 va = ((const float4*)(a + row * 1024))[tid];
    float4 vr = ((const float4*)(rb + row * 1024))[tid];
    float x0 = va.x + vr.x, x1 = va.y + vr.y, x2 = va.z + vr.z, x3 = va.w + vr.w;
    float s = x0 + x1 + x2 + x3;
    float sq = x0 * x0 + x1 * x1 + x2 * x2 + x3 * x3;
#pragma unroll
    for (int d = 1; d < 64; d <<= 1) { s += __shfl_xor(s, d); sq += __shfl_xor(sq, d); }
    __shared__ float ss[4], ssq[4];
    int wave = tid >> 6, lane = tid & 63;
    if (lane == 0) { ss[wave] = s; ssq[wave] = sq; }
    __syncthreads();
    s = ss[0] + ss[1] + ss[2] + ss[3];
    sq = ssq[0] + ssq[1] + ssq[2] + ssq[3];
    float mean = s * (1.0f / 1024.0f);
    float var = sq * (1.0f / 1024.0f) - mean * mean;
    float rstd = rsqrtf(var + 1e-5f);
    float4 vg = ((const float4*)g)[tid];
    float4 vb = ((const float4*)bb)[tid];
    float y0 = (x0 - mean) * rstd * vg.x + vb.x;
    float y1 = (x1 - mean) * rstd * vg.y + vb.y;
    float y2 = (x2 - mean) * rstd * vg.z + vb.z;
    float y3 = (x3 - mean) * rstd * vg.w + vb.w;
    float4 o; o.x = y0; o.y = y1; o.z = y2; o.w = y3;
    ((float4*)(outf + row * 1024))[tid] = o;
    ushort4 ob; ob.x = f2bf(y0); ob.y = f2bf(y1); ob.z = f2bf(y2); ob.w = f2bf(y3);
    ((ushort4*)(outb + row * 1024))[tid] = ob;
}

extern "C" void kernel_launch(void* const* d_in, const int* in_sizes, int n_in,
                              void* d_out, int out_size, void* d_ws, size_t ws_size,
                              hipStream_t stream) {
    const float* x    = (const float*)d_in[0];
    const float* enc  = (const float*)d_in[1];
    const int*   mask = (const int*)d_in[2];
    const float* q1W  = (const float*)d_in[3];
    const float* w1W  = (const float*)d_in[4];
    const float* o1W  = (const float*)d_in[5];
    const float* q2W  = (const float*)d_in[6];
    const float* w2W  = (const float*)d_in[7];
    const float* o2W  = (const float*)d_in[8];
    const float* ffW1 = (const float*)d_in[9];
    const float* ffb1 = (const float*)d_in[10];
    const float* ffW2 = (const float*)d_in[11];
    const float* ffb2 = (const float*)d_in[12];
    const float* g1 = (const float*)d_in[13];
    const float* b1 = (const float*)d_in[14];
    const float* g2 = (const float*)d_in[15];
    const float* b2 = (const float*)d_in[16];
    const float* g3 = (const float*)d_in[17];
    const float* b3 = (const float*)d_in[18];
    float* outp = (float*)d_out;

    const int T = 4096;   // B*L
    const int D = 1024;
    const int F = 4096;   // MLP

    char* ws = (char*)d_ws;
    auto alloc = [&](size_t sz) { char* p = ws; ws += (sz + 255) & ~(size_t)255; return p; };
    unsigned short* qw1Wt = (unsigned short*)alloc((size_t)2 * D * D * 2); // fused [2048][1024]
    unsigned short* o1Wt  = (unsigned short*)alloc((size_t)D * D * 2);
    unsigned short* q2Wt  = (unsigned short*)alloc((size_t)D * D * 2);
    unsigned short* w2Wt  = (unsigned short*)alloc((size_t)D * D * 2);
    unsigned short* o2Wt  = (unsigned short*)alloc((size_t)D * D * 2);
    unsigned short* ffW1t = (unsigned short*)alloc((size_t)F * D * 2);
    unsigned short* ffW2t = (unsigned short*)alloc((size_t)D * F * 2);
    unsigned short* xb    = (unsigned short*)alloc((size_t)T * D * 2);
    unsigned short* encb  = (unsigned short*)alloc((size_t)T * D * 2);
    unsigned short* Qhb   = (unsigned short*)alloc((size_t)T * D * 2);
    unsigned short* Khb   = (unsigned short*)alloc((size_t)T * D * 2);
    unsigned short* KhTb  = (unsigned short*)alloc((size_t)T * D * 2);
    unsigned short* attnb = (unsigned short*)alloc((size_t)T * D * 2);
    float*          projf = (float*)alloc((size_t)T * D * 4);
    float*          x1f   = (float*)alloc((size_t)T * D * 4);
    unsigned short* x1b   = (unsigned short*)alloc((size_t)T * D * 2);
    float*          x2f   = (float*)alloc((size_t)T * D * 4);
    unsigned short* x2b   = (unsigned short*)alloc((size_t)T * D * 2);
    unsigned short* S1    = (unsigned short*)alloc((size_t)T * F * 2); // 32 MB scratch: tmpqw / q2out+w2out / hb
    unsigned short* tmpqw = S1;                 // [4096][2048]
    unsigned short* q2o   = S1;                 // [4096][1024]
    unsigned short* w2o   = S1 + (size_t)T * D; // [4096][1024]
    unsigned short* hb    = S1;                 // [4096][4096]

    dim3 blk256(256);
    dim3 tblk(32, 8);

    // prologue casts
    cast_bf16_k<<<dim3((T * D / 4 + 255) / 256), blk256, 0, stream>>>(x, xb, T * D / 4);
    cast_bf16_k<<<dim3((T * D / 4 + 255) / 256), blk256, 0, stream>>>(enc, encb, T * D / 4);
    transpose_cast_k<<<dim3(D / 32, D / 32), tblk, 0, stream>>>(q1W, qw1Wt, D, D);
    transpose_cast_k<<<dim3(D / 32, D / 32), tblk, 0, stream>>>(w1W, qw1Wt + (size_t)D * D, D, D);
    transpose_cast_k<<<dim3(D / 32, D / 32), tblk, 0, stream>>>(o1W, o1Wt, D, D);
    transpose_cast_k<<<dim3(D / 32, D / 32), tblk, 0, stream>>>(q2W, q2Wt, D, D);
    transpose_cast_k<<<dim3(D / 32, D / 32), tblk, 0, stream>>>(w2W, w2Wt, D, D);
    transpose_cast_k<<<dim3(D / 32, D / 32), tblk, 0, stream>>>(o2W, o2Wt, D, D);
    transpose_cast_k<<<dim3(F / 32, D / 32), tblk, 0, stream>>>(ffW1, ffW1t, D, F);
    transpose_cast_k<<<dim3(D / 32, F / 32), tblk, 0, stream>>>(ffW2, ffW2t, F, D);

    // ---- self attention ----
    gemm_bt2_k<4><<<dim3(2 * D / 128, T / 128), blk256, 0, stream>>>(xb, qw1Wt, tmpqw, nullptr, T, 2 * D, D);
    split_heads_k<<<dim3(T / 16), blk256, 0, stream>>>(tmpqw, Qhb, 2 * D, 0);
    split_heads_k<<<dim3(T / 16), blk256, 0, stream>>>(tmpqw, Khb, 2 * D, D);
    transpose_heads_k<<<dim3(32, 32), blk256, 0, stream>>>(Khb, KhTb);
    flash_attn2_k<<<dim3(32, 32), blk256, 0, stream>>>(Qhb, Khb, KhTb, nullptr, attnb, 0);
    gemm_bt2_k<0><<<dim3(D / 128, T / 128), blk256, 0, stream>>>(attnb, o1Wt, projf, nullptr, T, D, D);
    resid_ln_k<<<dim3(T), blk256, 0, stream>>>(x, projf, g1, b1, x1f, x1b);

    // ---- cross attention ----
    gemm_bt2_k<4><<<dim3(D / 128, T / 128), blk256, 0, stream>>>(x1b, q2Wt, q2o, nullptr, T, D, D);
    split_heads_k<<<dim3(T / 16), blk256, 0, stream>>>(q2o, Qhb, D, 0);
    gemm_bt2_k<4><<<dim3(D / 128, T / 128), blk256, 0, stream>>>(encb, w2Wt, w2o, nullptr, T, D, D);
    split_heads_k<<<dim3(T / 16), blk256, 0, stream>>>(w2o, Khb, D, 0);
    transpose_heads_k<<<dim3(32, 32), blk256, 0, stream>>>(Khb, KhTb);
    flash_attn2_k<<<dim3(32, 32), blk256, 0, stream>>>(Qhb, Khb, KhTb, mask, attnb, 1);
    gemm_bt2_k<0><<<dim3(D / 128, T / 128), blk256, 0, stream>>>(attnb, o2Wt, projf, nullptr, T, D, D);
    resid_ln_k<<<dim3(T), blk256, 0, stream>>>(x1f, projf, g2, b2, x2f, x2b);

    // ---- feed forward ----
    gemm_bt2_k<2><<<dim3(F / 128, T / 128), blk256, 0, stream>>>(x2b, ffW1t, hb, ffb1, T, F, D);
    gemm_bt2_k<3><<<dim3(D / 128, T / 128), blk256, 0, stream>>>(hb, ffW2t, projf, ffb2, T, D, F);
    resid_ln_k<<<dim3(T), blk256, 0, stream>>>(x2f, projf, g3, b3, outp, x2b);
}

// Round 3
// 715.521 us; speedup vs baseline: 1.4925x; 1.1749x over previous
//
#include <hip/hip_runtime.h>
#include <hip/hip_bf16.h>
#include <math.h>
#include <stdint.h>

typedef __attribute__((ext_vector_type(8))) short bf16x8_t;
typedef __attribute__((ext_vector_type(4))) float f32x4_t;

#define LOG2E 1.4426950408889634f
#define GLB(p) ((const __attribute__((address_space(1))) void*)(p))
#define LDS(p) ((__attribute__((address_space(3))) void*)(p))

__device__ __forceinline__ unsigned short f2bf(float f) {
    union { float f; unsigned int u; } v; v.f = f;
    unsigned int r = v.u + 0x7FFFu + ((v.u >> 16) & 1u);
    return (unsigned short)(r >> 16);
}

__device__ __forceinline__ unsigned int pack2bf(float a, float b) {
#if __has_builtin(__builtin_amdgcn_cvt_pk_bf16_f32)
    auto r = __builtin_amdgcn_cvt_pk_bf16_f32(a, b);
    unsigned int u;
    __builtin_memcpy(&u, &r, 4);
    return u;
#else
    return (unsigned int)f2bf(a) | ((unsigned int)f2bf(b) << 16);
#endif
}

// ---------------- elementwise cast fp32 -> bf16 ----------------
__global__ void cast_bf16_k(const float* __restrict__ in, unsigned short* __restrict__ out, int n4) {
    int i = blockIdx.x * blockDim.x + threadIdx.x;
    if (i < n4) {
        float4 v = ((const float4*)in)[i];
        ushort4 o;
        o.x = f2bf(v.x); o.y = f2bf(v.y); o.z = f2bf(v.z); o.w = f2bf(v.w);
        ((ushort4*)out)[i] = o;
    }
}

// ---------------- transpose + cast: W (K x N) fp32 -> Wt (N x K) bf16 ----------------
__global__ void transpose_cast_k(const float* __restrict__ W, unsigned short* __restrict__ Wt,
                                 int K, int N) {
    __shared__ float tile[32][33];
    int k0 = blockIdx.y * 32, n0 = blockIdx.x * 32;
    int tx = threadIdx.x, ty = threadIdx.y; // 32 x 8
#pragma unroll
    for (int i = 0; i < 32; i += 8)
        tile[ty + i][tx] = W[(long)(k0 + ty + i) * N + n0 + tx];
    __syncthreads();
#pragma unroll
    for (int i = 0; i < 32; i += 8)
        Wt[(long)(n0 + ty + i) * K + k0 + tx] = f2bf(tile[tx][ty + i]);
}

// ---------------- split heads: in [4096][stride] (col=coloff + d*16+h) -> out [B*16+h][2048][64] ----------------
__global__ __launch_bounds__(256) void split_heads_k(const unsigned short* __restrict__ in,
                                                     unsigned short* __restrict__ out,
                                                     int stride, int coloff) {
    __shared__ __align__(16) unsigned short t[16][1024];
    long l0 = (long)blockIdx.x * 16;
    int tid = threadIdx.x;
    for (int c = tid; c < 2048; c += 256) {
        int r = c >> 7, col = (c & 127) * 8;
        *(uint4*)(&t[r][col]) = *(const uint4*)(in + (l0 + r) * stride + coloff + col);
    }
    __syncthreads();
    int h = tid >> 4, lr = tid & 15;
    long l = l0 + lr;
    int b = (int)(l >> 11);
    int ll = (int)(l & 2047);
    unsigned short* op = out + ((long)(b * 16 + h) * 2048 + ll) * 64;
#pragma unroll
    for (int d8 = 0; d8 < 64; d8 += 8) {
        union { uint4 v; unsigned short s[8]; } u;
#pragma unroll
        for (int j = 0; j < 8; j++) u.s[j] = t[lr][(d8 + j) * 16 + h];
        *(uint4*)(op + d8) = u.v;
    }
}

// ---------------- per-head transpose + per-64-chunk column permutation ----------------
// Kh [bh][2048][64] -> KhT [bh][64][2048] where within each 64-wide m-chunk,
// position p holds m = (p>>2) + (p&3)*16  (perm(m) = (m&15)*4 + (m>>4)).
__global__ __launch_bounds__(256) void transpose_heads_perm_k(const unsigned short* __restrict__ in,
                                                              unsigned short* __restrict__ out) {
    __shared__ unsigned short t[64][72];
    int bh = blockIdx.y;
    int m0 = blockIdx.x * 64;
    int tid = threadIdx.x;
    for (int c = tid; c < 512; c += 256) {
        int r = c >> 3, col = (c & 7) * 8;
        *(uint4*)(&t[r][col]) = *(const uint4*)(in + ((long)bh * 2048 + m0 + r) * 64 + col);
    }
    __syncthreads();
    for (int c = tid; c < 512; c += 256) {
        int d = c >> 3, pbase = (c & 7) * 8;
        union { uint4 v; unsigned short s[8]; } u;
#pragma unroll
        for (int j = 0; j < 8; j++) {
            int p = pbase + j;
            int m = (p >> 2) + (p & 3) * 16;
            u.s[j] = t[m][d];
        }
        *(uint4*)(out + ((long)bh * 64 + d) * 2048 + m0 + pbase) = u.v;
    }
}

// ---------------- GEMM: C(M,N) = A(M,K) @ Bt(N,K)^T, bf16 in, fp32 acc ----------------
// EP: 0 = fp32 out, 2 = bias+gelu -> bf16 out, 3 = bias -> fp32 out, 4 = bf16 out
template <int EP>
__global__ __launch_bounds__(256) void gemm_bt2_k(const unsigned short* __restrict__ A,
                                                  const unsigned short* __restrict__ Bt,
                                                  void* __restrict__ outp,
                                                  const float* __restrict__ bias,
                                                  int M, int N, int K) {
    __shared__ __align__(16) unsigned short As[128 * 32];
    __shared__ __align__(16) unsigned short Bs[128 * 32];
    int tid = threadIdx.x;
    int wave = tid >> 6, lane = tid & 63;
    int wm = wave >> 1, wn = wave & 1;
    int quad = lane >> 4, l16 = lane & 15;
    int bm = blockIdx.y * 128, bn = blockIdx.x * 128;

    f32x4_t acc[4][4] = {};

    const unsigned short* Ag0 = A + (long)(bm + (tid >> 2)) * K + (tid & 3) * 8;
    const unsigned short* Ag1 = A + (long)(bm + (tid >> 2) + 64) * K + (tid & 3) * 8;
    const unsigned short* Bg0 = Bt + (long)(bn + (tid >> 2)) * K + (tid & 3) * 8;
    const unsigned short* Bg1 = Bt + (long)(bn + (tid >> 2) + 64) * K + (tid & 3) * 8;
    unsigned short* Al0 = As + tid * 8;
    unsigned short* Al1 = As + tid * 8 + 2048;
    unsigned short* Bl0 = Bs + tid * 8;
    unsigned short* Bl1 = Bs + tid * 8 + 2048;

    for (int k0 = 0; k0 < K; k0 += 32) {
        __syncthreads();
        __builtin_amdgcn_global_load_lds(GLB(Ag0 + k0), LDS(Al0), 16, 0, 0);
        __builtin_amdgcn_global_load_lds(GLB(Ag1 + k0), LDS(Al1), 16, 0, 0);
        __builtin_amdgcn_global_load_lds(GLB(Bg0 + k0), LDS(Bl0), 16, 0, 0);
        __builtin_amdgcn_global_load_lds(GLB(Bg1 + k0), LDS(Bl1), 16, 0, 0);
        __syncthreads();
        bf16x8_t af[4], bfr[4];
#pragma unroll
        for (int t = 0; t < 4; t++) {
            af[t]  = *(const bf16x8_t*)(As + (wm * 64 + t * 16 + l16) * 32 + quad * 8);
            bfr[t] = *(const bf16x8_t*)(Bs + (wn * 64 + t * 16 + l16) * 32 + quad * 8);
        }
#pragma unroll
        for (int mt = 0; mt < 4; mt++)
#pragma unroll
            for (int nt = 0; nt < 4; nt++)
                acc[mt][nt] = __builtin_amdgcn_mfma_f32_16x16x32_bf16(af[mt], bfr[nt], acc[mt][nt], 0, 0, 0);
    }

#pragma unroll
    for (int mt = 0; mt < 4; mt++)
#pragma unroll
        for (int nt = 0; nt < 4; nt++)
#pragma unroll
            for (int r = 0; r < 4; r++) {
                int gm = bm + wm * 64 + mt * 16 + quad * 4 + r;
                int gn = bn + wn * 64 + nt * 16 + l16;
                float v = acc[mt][nt][r];
                if (EP == 0) {
                    ((float*)outp)[(long)gm * N + gn] = v;
                } else if (EP == 2) {
                    v += bias[gn];
                    v = 0.5f * v * (1.0f + erff(v * 0.70710678118654752f));
                    ((unsigned short*)outp)[(long)gm * N + gn] = f2bf(v);
                } else if (EP == 3) {
                    ((float*)outp)[(long)gm * N + gn] = v + bias[gn];
                } else {
                    ((unsigned short*)outp)[(long)gm * N + gn] = f2bf(v);
                }
            }
}

// ---------------- flash attention v3: streaming softmax, no running max ----------------
// Qh, Kh: [bh][2048][64]; KhTp: [bh][64][2048] (m-permuted per 64-chunk).
// out: [4096][1024] bf16 (col=d*16+h). mask pre-scale -1e9 == mf=-1e10 in log2 domain.
template <int USE_MASK>
__global__ __launch_bounds__(256) void flash_attn3_k(const unsigned short* __restrict__ Qh,
                                                     const unsigned short* __restrict__ Kh,
                                                     const unsigned short* __restrict__ KhTp,
                                                     const int* __restrict__ maskp,
                                                     unsigned short* __restrict__ out) {
    __shared__ __align__(16) unsigned short Qs[64 * 72];
    __shared__ __align__(16) unsigned short K1[64 * 72]; // [m][d] natural
    __shared__ __align__(16) unsigned short K2[64 * 72]; // [d][p] permuted m
    __shared__ __align__(16) unsigned short Ps[64 * 72]; // [l][p] permuted m
    __shared__ float maskf[64];

    int tid = threadIdx.x;
    int wave = tid >> 6, lane = tid & 63;
    int quad = lane >> 4, l16 = lane & 15;
    int bh = blockIdx.y, b = bh >> 4, h = bh & 15;
    int l0 = blockIdx.x * 64;
    const unsigned short* Qbase = Qh + ((long)bh * 2048 + l0) * 64;
    const unsigned short* Kbase = Kh + (long)bh * 2048 * 64;
    const unsigned short* KTbase = KhTp + (long)bh * 64 * 2048;

    for (int c = tid; c < 512; c += 256) {
        int row = c >> 3, col = (c & 7) * 8;
        *(uint4*)(Qs + row * 72 + col) = *(const uint4*)(Qbase + row * 64 + col);
    }

    const float C1 = 0.125f * LOG2E;
    f32x4_t acc_o[4] = {};
    float rs[4] = {0.f, 0.f, 0.f, 0.f};

    int srow = tid >> 3, scol = (tid & 7) * 8;
    int srow2 = (tid + 256) >> 3, scol2 = ((tid + 256) & 7) * 8;

    for (int m0 = 0; m0 < 2048; m0 += 64) {
        __syncthreads();
        *(uint4*)(K1 + srow * 72 + scol)   = *(const uint4*)(Kbase + (long)(m0 + srow) * 64 + scol);
        *(uint4*)(K1 + srow2 * 72 + scol2) = *(const uint4*)(Kbase + (long)(m0 + srow2) * 64 + scol2);
        *(uint4*)(K2 + srow * 72 + scol)   = *(const uint4*)(KTbase + (long)srow * 2048 + m0 + scol);
        *(uint4*)(K2 + srow2 * 72 + scol2) = *(const uint4*)(KTbase + (long)srow2 * 2048 + m0 + scol2);
        if (USE_MASK && tid < 64) maskf[tid] = maskp[b * 2048 + m0 + tid] ? -1e10f : 0.0f;
        __syncthreads();

        // S = Q @ Ktile^T : wave handles 16 Q rows (band = wave*16), 64 m cols
        f32x4_t sacc[4] = {};
#pragma unroll
        for (int kk = 0; kk < 2; kk++) {
            bf16x8_t af = *(const bf16x8_t*)(Qs + (wave * 16 + l16) * 72 + kk * 32 + quad * 8);
#pragma unroll
            for (int nt = 0; nt < 4; nt++) {
                bf16x8_t bfr = *(const bf16x8_t*)(K1 + (nt * 16 + l16) * 72 + kk * 32 + quad * 8);
                sacc[nt] = __builtin_amdgcn_mfma_f32_16x16x32_bf16(af, bfr, sacc[nt], 0, 0, 0);
            }
        }

        float mf0 = 0.f, mf1 = 0.f, mf2 = 0.f, mf3 = 0.f;
        if (USE_MASK) {
            mf0 = maskf[l16]; mf1 = maskf[16 + l16];
            mf2 = maskf[32 + l16]; mf3 = maskf[48 + l16];
        }

        // p = exp2(s*C1 + mf); per-lane row-sum; write P b64 (4 bf16, permuted cols)
#pragma unroll
        for (int r = 0; r < 4; r++) {
            float p0 = exp2f(fmaf(sacc[0][r], C1, mf0));
            float p1 = exp2f(fmaf(sacc[1][r], C1, mf1));
            float p2 = exp2f(fmaf(sacc[2][r], C1, mf2));
            float p3 = exp2f(fmaf(sacc[3][r], C1, mf3));
            rs[r] += (p0 + p1) + (p2 + p3);
            uint2 pk; pk.x = pack2bf(p0, p1); pk.y = pack2bf(p2, p3);
            *(uint2*)(Ps + (wave * 16 + quad * 4 + r) * 72 + l16 * 4) = pk;
        }

        // O += P @ Ktile : A = own band of Ps (permuted), B = K2 (permuted) — sum invariant
#pragma unroll
        for (int kk = 0; kk < 2; kk++) {
            bf16x8_t af = *(const bf16x8_t*)(Ps + (wave * 16 + l16) * 72 + kk * 32 + quad * 8);
#pragma unroll
            for (int nt = 0; nt < 4; nt++) {
                bf16x8_t bfr = *(const bf16x8_t*)(K2 + (nt * 16 + l16) * 72 + kk * 32 + quad * 8);
                acc_o[nt] = __builtin_amdgcn_mfma_f32_16x16x32_bf16(af, bfr, acc_o[nt], 0, 0, 0);
            }
        }
    }

    // single final reduction of row sums across the 16 l16 lanes
#pragma unroll
    for (int r = 0; r < 4; r++) {
#pragma unroll
        for (int d = 1; d < 16; d <<= 1) rs[r] += __shfl_xor(rs[r], d);
    }

#pragma unroll
    for (int r = 0; r < 4; r++) {
        float inv = 1.0f / rs[r];
        int l = l0 + wave * 16 + quad * 4 + r;
#pragma unroll
        for (int nt = 0; nt < 4; nt++) {
            int d = nt * 16 + l16;
            out[((long)(b * 2048 + l)) * 1024 + d * 16 + h] = f2bf(acc_o[nt][r] * inv);
        }
    }
}

// ---------------- residual + layernorm: out = LN(a + rb) * g + b ----------------
__global__ __launch_bounds__(256) void resid_ln_k(const float* __restrict__ a,
                                                  const float* __restrict__ rb,
                                                  const float* __restrict__ g,
                                                  const float* __restrict__ bb,
                                                  float* __restrict__ outf,
                                                  unsigned short* __restrict__ outb) {
    long row = blockIdx.x;
    int tid = threadIdx.x;
    float4 va = ((const float4*)(a + row * 1024))[tid];
    float4 vr = ((const float4*)(rb + row * 1024))[tid];
    float x0 = va.x + vr.x, x1 = va.y + vr.y, x2 = va.z + vr.z, x3 = va.w + vr.w;
    float s = x0 + x1 + x2 + x3;
    float sq = x0 * x0 + x1 * x1 + x2 * x2 + x3 * x3;
#pragma unroll
    for (int d = 1; d < 64; d <<= 1) { s += __shfl_xor(s, d); sq += __shfl_xor(sq, d); }
    __shared__ float ss[4], ssq[4];
    int wave = tid >> 6, lane = tid & 63;
    if (lane == 0) { ss[wave] = s; ssq[wave] = sq; }
    __syncthreads();
    s = ss[0] + ss[1] + ss[2] + ss[3];
    sq = ssq[0] + ssq[1] + ssq[2] + ssq[3];
    float mean = s * (1.0f / 1024.0f);
    float var = sq * (1.0f / 1024.0f) - mean * mean;
    float rstd = rsqrtf(var + 1e-5f);
    float4 vg = ((const float4*)g)[tid];
    float4 vb = ((const float4*)bb)[tid];
    float y0 = (x0 - mean) * rstd * vg.x + vb.x;
    float y1 = (x1 - mean) * rstd * vg.y + vb.y;
    float y2 = (x2 - mean) * rstd * vg.z + vb.z;
    float y3 = (x3 - mean) * rstd * vg.w + vb.w;
    float4 o; o.x = y0; o.y = y1; o.z = y2; o.w = y3;
    ((float4*)(outf + row * 1024))[tid] = o;
    ushort4 ob; ob.x = f2bf(y0); ob.y = f2bf(y1); ob.z = f2bf(y2); ob.w = f2bf(y3);
    ((ushort4*)(outb + row * 1024))[tid] = ob;
}

extern "C" void kernel_launch(void* const* d_in, const int* in_sizes, int n_in,
                              void* d_out, int out_size, void* d_ws, size_t ws_size,
                              hipStream_t stream) {
    const float* x    = (const float*)d_in[0];
    const float* enc  = (const float*)d_in[1];
    const int*   mask = (const int*)d_in[2];
    const float* q1W  = (const float*)d_in[3];
    const float* w1W  = (const float*)d_in[4];
    const float* o1W  = (const float*)d_in[5];
    const float* q2W  = (const float*)d_in[6];
    const float* w2W  = (const float*)d_in[7];
    const float* o2W  = (const float*)d_in[8];
    const float* ffW1 = (const float*)d_in[9];
    const float* ffb1 = (const float*)d_in[10];
    const float* ffW2 = (const float*)d_in[11];
    const float* ffb2 = (const float*)d_in[12];
    const float* g1 = (const float*)d_in[13];
    const float* b1 = (const float*)d_in[14];
    const float* g2 = (const float*)d_in[15];
    const float* b2 = (const float*)d_in[16];
    const float* g3 = (const float*)d_in[17];
    const float* b3 = (const float*)d_in[18];
    float* outp = (float*)d_out;

    const int T = 4096;   // B*L
    const int D = 1024;
    const int F = 4096;   // MLP

    char* ws = (char*)d_ws;
    auto alloc = [&](size_t sz) { char* p = ws; ws += (sz + 255) & ~(size_t)255; return p; };
    unsigned short* qw1Wt = (unsigned short*)alloc((size_t)2 * D * D * 2); // fused [2048][1024]
    unsigned short* o1Wt  = (unsigned short*)alloc((size_t)D * D * 2);
    unsigned short* q2Wt  = (unsigned short*)alloc((size_t)D * D * 2);
    unsigned short* w2Wt  = (unsigned short*)alloc((size_t)D * D * 2);
    unsigned short* o2Wt  = (unsigned short*)alloc((size_t)D * D * 2);
    unsigned short* ffW1t = (unsigned short*)alloc((size_t)F * D * 2);
    unsigned short* ffW2t = (unsigned short*)alloc((size_t)D * F * 2);
    unsigned short* xb    = (unsigned short*)alloc((size_t)T * D * 2);
    unsigned short* encb  = (unsigned short*)alloc((size_t)T * D * 2);
    unsigned short* Qhb   = (unsigned short*)alloc((size_t)T * D * 2);
    unsigned short* Khb   = (unsigned short*)alloc((size_t)T * D * 2);
    unsigned short* KhTb  = (unsigned short*)alloc((size_t)T * D * 2);
    unsigned short* attnb = (unsigned short*)alloc((size_t)T * D * 2);
    float*          projf = (float*)alloc((size_t)T * D * 4);
    float*          x1f   = (float*)alloc((size_t)T * D * 4);
    unsigned short* x1b   = (unsigned short*)alloc((size_t)T * D * 2);
    float*          x2f   = (float*)alloc((size_t)T * D * 4);
    unsigned short* x2b   = (unsigned short*)alloc((size_t)T * D * 2);
    unsigned short* S1    = (unsigned short*)alloc((size_t)T * F * 2); // 32 MB scratch
    unsigned short* tmpqw = S1;                 // [4096][2048]
    unsigned short* q2o   = S1;                 // [4096][1024]
    unsigned short* w2o   = S1 + (size_t)T * D; // [4096][1024]
    unsigned short* hb    = S1;                 // [4096][4096]

    dim3 blk256(256);
    dim3 tblk(32, 8);

    // prologue casts
    cast_bf16_k<<<dim3((T * D / 4 + 255) / 256), blk256, 0, stream>>>(x, xb, T * D / 4);
    cast_bf16_k<<<dim3((T * D / 4 + 255) / 256), blk256, 0, stream>>>(enc, encb, T * D / 4);
    transpose_cast_k<<<dim3(D / 32, D / 32), tblk, 0, stream>>>(q1W, qw1Wt, D, D);
    transpose_cast_k<<<dim3(D / 32, D / 32), tblk, 0, stream>>>(w1W, qw1Wt + (size_t)D * D, D, D);
    transpose_cast_k<<<dim3(D / 32, D / 32), tblk, 0, stream>>>(o1W, o1Wt, D, D);
    transpose_cast_k<<<dim3(D / 32, D / 32), tblk, 0, stream>>>(q2W, q2Wt, D, D);
    transpose_cast_k<<<dim3(D / 32, D / 32), tblk, 0, stream>>>(w2W, w2Wt, D, D);
    transpose_cast_k<<<dim3(D / 32, D / 32), tblk, 0, stream>>>(o2W, o2Wt, D, D);
    transpose_cast_k<<<dim3(F / 32, D / 32), tblk, 0, stream>>>(ffW1, ffW1t, D, F);
    transpose_cast_k<<<dim3(D / 32, F / 32), tblk, 0, stream>>>(ffW2, ffW2t, F, D);

    // ---- self attention ----
    gemm_bt2_k<4><<<dim3(2 * D / 128, T / 128), blk256, 0, stream>>>(xb, qw1Wt, tmpqw, nullptr, T, 2 * D, D);
    split_heads_k<<<dim3(T / 16), blk256, 0, stream>>>(tmpqw, Qhb, 2 * D, 0);
    split_heads_k<<<dim3(T / 16), blk256, 0, stream>>>(tmpqw, Khb, 2 * D, D);
    transpose_heads_perm_k<<<dim3(32, 32), blk256, 0, stream>>>(Khb, KhTb);
    flash_attn3_k<0><<<dim3(32, 32), blk256, 0, stream>>>(Qhb, Khb, KhTb, nullptr, attnb);
    gemm_bt2_k<0><<<dim3(D / 128, T / 128), blk256, 0, stream>>>(attnb, o1Wt, projf, nullptr, T, D, D);
    resid_ln_k<<<dim3(T), blk256, 0, stream>>>(x, projf, g1, b1, x1f, x1b);

    // ---- cross attention ----
    gemm_bt2_k<4><<<dim3(D / 128, T / 128), blk256, 0, stream>>>(x1b, q2Wt, q2o, nullptr, T, D, D);
    split_heads_k<<<dim3(T / 16), blk256, 0, stream>>>(q2o, Qhb, D, 0);
    gemm_bt2_k<4><<<dim3(D / 128, T / 128), blk256, 0, stream>>>(encb, w2Wt, w2o, nullptr, T, D, D);
    split_heads_k<<<dim3(T / 16), blk256, 0, stream>>>(w2o, Khb, D, 0);
    transpose_heads_perm_k<<<dim3(32, 32), blk256, 0, stream>>>(Khb, KhTb);
    flash_attn3_k<1><<<dim3(32, 32), blk256, 0, stream>>>(Qhb, Khb, KhTb, mask, attnb);
    gemm_bt2_k<0><<<dim3(D / 128, T / 128), blk256, 0, stream>>>(attnb, o2Wt, projf, nullptr, T, D, D);
    resid_ln_k<<<dim3(T), blk256, 0, stream>>>(x1f, projf, g2, b2, x2f, x2b);

    // ---- feed forward ----
    gemm_bt2_k<2><<<dim3(F / 128, T / 128), blk256, 0, stream>>>(x2b, ffW1t, hb, ffb1, T, F, D);
    gemm_bt2_k<3><<<dim3(D / 128, T / 128), blk256, 0, stream>>>(hb, ffW2t, projf, ffb2, T, D, F);
    resid_ln_k<<<dim3(T), blk256, 0, stream>>>(x2f, projf, g3, b3, outp, x2b);
}

// Round 4
// 642.770 us; speedup vs baseline: 1.6615x; 1.1132x over previous
//
#include <hip/hip_runtime.h>
#include <hip/hip_bf16.h>
#include <math.h>
#include <stdint.h>

typedef __attribute__((ext_vector_type(8))) short bf16x8_t;
typedef __attribute__((ext_vector_type(4))) float f32x4_t;

#define LOG2E 1.4426950408889634f
#define GLB(p) ((const __attribute__((address_space(1))) void*)(p))
#define LDS(p) ((__attribute__((address_space(3))) void*)(p))

__device__ __forceinline__ unsigned short f2bf(float f) {
    union { float f; unsigned int u; } v; v.f = f;
    unsigned int r = v.u + 0x7FFFu + ((v.u >> 16) & 1u);
    return (unsigned short)(r >> 16);
}

__device__ __forceinline__ unsigned int pack2bf(float a, float b) {
#if __has_builtin(__builtin_amdgcn_cvt_pk_bf16_f32)
    auto r = __builtin_amdgcn_cvt_pk_bf16_f32(a, b);
    unsigned int u;
    __builtin_memcpy(&u, &r, 4);
    return u;
#else
    return (unsigned int)f2bf(a) | ((unsigned int)f2bf(b) << 16);
#endif
}

// ---------------- fused cast fp32 -> bf16 for x and enc ----------------
__global__ void cast2_bf16_k(const float* __restrict__ inA, unsigned short* __restrict__ outA,
                             const float* __restrict__ inB, unsigned short* __restrict__ outB,
                             int n4) {
    const float* in = blockIdx.y ? inB : inA;
    unsigned short* out = blockIdx.y ? outB : outA;
    int i = blockIdx.x * blockDim.x + threadIdx.x;
    if (i < n4) {
        float4 v = ((const float4*)in)[i];
        ushort4 o;
        o.x = f2bf(v.x); o.y = f2bf(v.y); o.z = f2bf(v.z); o.w = f2bf(v.w);
        ((ushort4*)out)[i] = o;
    }
}

// ---------------- fused weight transpose+cast: all 8 weights in one dispatch ----------------
// tiles: 6 x (1024x1024) = 6144, ffW1 (1024x4096) = 4096, ffW2 (4096x1024) = 4096 -> 14336
__global__ void transpose_all_k(const float* __restrict__ s0, const float* __restrict__ s1,
                                const float* __restrict__ s2, const float* __restrict__ s3,
                                const float* __restrict__ s4, const float* __restrict__ s5,
                                const float* __restrict__ s6, const float* __restrict__ s7,
                                unsigned short* __restrict__ d0, unsigned short* __restrict__ d1,
                                unsigned short* __restrict__ d2, unsigned short* __restrict__ d3,
                                unsigned short* __restrict__ d4, unsigned short* __restrict__ d5,
                                unsigned short* __restrict__ d6, unsigned short* __restrict__ d7) {
    __shared__ float tile[32][33];
    int idx = blockIdx.x;
    const float* W; unsigned short* Wt; int K, N, bx, by;
    if (idx < 6144) {
        int which = idx >> 10, t = idx & 1023;
        bx = t & 31; by = t >> 5; K = 1024; N = 1024;
        switch (which) {
            case 0: W = s0; Wt = d0; break;
            case 1: W = s1; Wt = d1; break;
            case 2: W = s2; Wt = d2; break;
            case 3: W = s3; Wt = d3; break;
            case 4: W = s4; Wt = d4; break;
            default: W = s5; Wt = d5; break;
        }
    } else if (idx < 10240) {
        int t = idx - 6144;
        bx = t & 127; by = t >> 7; K = 1024; N = 4096;
        W = s6; Wt = d6;
    } else {
        int t = idx - 10240;
        bx = t & 31; by = t >> 5; K = 4096; N = 1024;
        W = s7; Wt = d7;
    }
    int k0 = by * 32, n0 = bx * 32;
    int tx = threadIdx.x, ty = threadIdx.y; // 32 x 8
#pragma unroll
    for (int i = 0; i < 32; i += 8)
        tile[ty + i][tx] = W[(long)(k0 + ty + i) * N + n0 + tx];
    __syncthreads();
#pragma unroll
    for (int i = 0; i < 32; i += 8)
        Wt[(long)(n0 + ty + i) * K + k0 + tx] = f2bf(tile[tx][ty + i]);
}

// ---------------- fused Q+K head split with XOR-8 group swizzle ----------------
// in [4096][stride] (col = qoff/koff + d*16+h) -> out [b*16+h][2048][64],
// 8-short group g stored at physical slot g ^ (l & 7).
__global__ __launch_bounds__(256) void split_qk_k(const unsigned short* __restrict__ inQ,
                                                  const unsigned short* __restrict__ inK,
                                                  int stride, int koff,
                                                  unsigned short* __restrict__ Qout,
                                                  unsigned short* __restrict__ Kout) {
    __shared__ __align__(16) unsigned short t[16][1024];
    long l0 = (long)blockIdx.x * 16;
    int tid = threadIdx.x;
    int h = tid >> 4, lr = tid & 15;
    long l = l0 + lr;
    int b = (int)(l >> 11);
    int ll = (int)(l & 2047);
    int sw = ll & 7;

    // phase Q
    for (int c = tid; c < 2048; c += 256) {
        int r = c >> 7, col = (c & 127) * 8;
        *(uint4*)(&t[r][col]) = *(const uint4*)(inQ + (l0 + r) * stride + col);
    }
    __syncthreads();
    {
        unsigned short* op = Qout + ((long)(b * 16 + h) * 2048 + ll) * 64;
#pragma unroll
        for (int g = 0; g < 8; g++) {
            union { uint4 v; unsigned short s[8]; } u;
#pragma unroll
            for (int j = 0; j < 8; j++) u.s[j] = t[lr][(g * 8 + j) * 16 + h];
            *(uint4*)(op + (g ^ sw) * 8) = u.v;
        }
    }
    __syncthreads();
    // phase K
    for (int c = tid; c < 2048; c += 256) {
        int r = c >> 7, col = (c & 127) * 8;
        *(uint4*)(&t[r][col]) = *(const uint4*)(inK + (l0 + r) * stride + koff + col);
    }
    __syncthreads();
    {
        unsigned short* op = Kout + ((long)(b * 16 + h) * 2048 + ll) * 64;
#pragma unroll
        for (int g = 0; g < 8; g++) {
            union { uint4 v; unsigned short s[8]; } u;
#pragma unroll
            for (int j = 0; j < 8; j++) u.s[j] = t[lr][(g * 8 + j) * 16 + h];
            *(uint4*)(op + (g ^ sw) * 8) = u.v;
        }
    }
}

// ---------------- per-head transpose + m-perm, deswizzle-in / swizzle-out ----------------
// Kh [bh][2048][64] (swizzled rows) -> KhT [bh][64][2048]; within each 64-chunk,
// logical position p holds m = (p>>2)+(p&3)*16; groups swizzled by (d & 7).
__global__ __launch_bounds__(256) void transpose_heads_perm_k(const unsigned short* __restrict__ in,
                                                              unsigned short* __restrict__ out) {
    __shared__ unsigned short t[64][72];
    int bh = blockIdx.y;
    int m0 = blockIdx.x * 64;
    int tid = threadIdx.x;
    for (int c = tid; c < 512; c += 256) {
        int r = c >> 3, gp = c & 7;
        int glog = gp ^ (r & 7);
        uint4 v = *(const uint4*)(in + ((long)bh * 2048 + m0 + r) * 64 + gp * 8);
        *(uint4*)(&t[r][glog * 8]) = v;
    }
    __syncthreads();
    for (int c = tid; c < 512; c += 256) {
        int d = c >> 3, pb = (c & 7) * 8;
        union { uint4 v; unsigned short s[8]; } u;
#pragma unroll
        for (int j = 0; j < 8; j++) {
            int p = pb + j;
            int m = (p >> 2) + (p & 3) * 16;
            u.s[j] = t[m][d];
        }
        int gph = (pb >> 3) ^ (d & 7);
        *(uint4*)(out + ((long)bh * 64 + d) * 2048 + m0 + gph * 8) = u.v;
    }
}

// ---------------- GEMM: C(M,N) = A(M,K) @ Bt(N,K)^T, bf16 in, fp32 acc ----------------
// BN = 128 or 64. blockIdx.z selects (A2,Bt2,out2) for fused twin GEMMs.
// EP: 0 = fp32 out, 2 = bias+gelu -> bf16 out, 3 = bias -> fp32 out, 4 = bf16 out
template <int EP, int BN>
__global__ __launch_bounds__(256) void gemm_k(const unsigned short* __restrict__ A,
                                              const unsigned short* __restrict__ Bt,
                                              void* __restrict__ outp,
                                              const float* __restrict__ bias,
                                              const unsigned short* __restrict__ A2,
                                              const unsigned short* __restrict__ Bt2,
                                              void* __restrict__ out2,
                                              int M, int N, int K) {
    if (blockIdx.z) { A = A2; Bt = Bt2; outp = out2; }
    __shared__ __align__(16) unsigned short As[128 * 32];
    __shared__ __align__(16) unsigned short Bs[BN * 32];
    const int NT = BN / 32;       // MFMA n-tiles per wave
    int tid = threadIdx.x;
    int wave = tid >> 6, lane = tid & 63;
    int wm = wave >> 1, wn = wave & 1;
    int quad = lane >> 4, l16 = lane & 15;
    int bm = blockIdx.y * 128, bn = blockIdx.x * BN;

    f32x4_t acc[4][NT] = {};

    const unsigned short* Ag0 = A + (long)(bm + (tid >> 2)) * K + (tid & 3) * 8;
    const unsigned short* Ag1 = A + (long)(bm + (tid >> 2) + 64) * K + (tid & 3) * 8;
    const unsigned short* Bg0 = Bt + (long)(bn + (tid >> 2)) * K + (tid & 3) * 8;
    const unsigned short* Bg1 = Bt + (long)(bn + (tid >> 2) + 64) * K + (tid & 3) * 8;
    unsigned short* Al0 = As + tid * 8;
    unsigned short* Al1 = As + tid * 8 + 2048;
    unsigned short* Bl0 = Bs + tid * 8;
    unsigned short* Bl1 = Bs + tid * 8 + 2048;

    for (int k0 = 0; k0 < K; k0 += 32) {
        __syncthreads();
        __builtin_amdgcn_global_load_lds(GLB(Ag0 + k0), LDS(Al0), 16, 0, 0);
        __builtin_amdgcn_global_load_lds(GLB(Ag1 + k0), LDS(Al1), 16, 0, 0);
        __builtin_amdgcn_global_load_lds(GLB(Bg0 + k0), LDS(Bl0), 16, 0, 0);
        if (BN == 128)
            __builtin_amdgcn_global_load_lds(GLB(Bg1 + k0), LDS(Bl1), 16, 0, 0);
        __syncthreads();
        bf16x8_t af[4], bfr[NT];
#pragma unroll
        for (int t = 0; t < 4; t++)
            af[t] = *(const bf16x8_t*)(As + (wm * 64 + t * 16 + l16) * 32 + quad * 8);
#pragma unroll
        for (int t = 0; t < NT; t++)
            bfr[t] = *(const bf16x8_t*)(Bs + (wn * (BN / 2) + t * 16 + l16) * 32 + quad * 8);
#pragma unroll
        for (int mt = 0; mt < 4; mt++)
#pragma unroll
            for (int nt = 0; nt < NT; nt++)
                acc[mt][nt] = __builtin_amdgcn_mfma_f32_16x16x32_bf16(af[mt], bfr[nt], acc[mt][nt], 0, 0, 0);
    }

#pragma unroll
    for (int mt = 0; mt < 4; mt++)
#pragma unroll
        for (int nt = 0; nt < NT; nt++)
#pragma unroll
            for (int r = 0; r < 4; r++) {
                int gm = bm + wm * 64 + mt * 16 + quad * 4 + r;
                int gn = bn + wn * (BN / 2) + nt * 16 + l16;
                float v = acc[mt][nt][r];
                if (EP == 0) {
                    ((float*)outp)[(long)gm * N + gn] = v;
                } else if (EP == 2) {
                    v += bias[gn];
                    v = 0.5f * v * (1.0f + erff(v * 0.70710678118654752f));
                    ((unsigned short*)outp)[(long)gm * N + gn] = f2bf(v);
                } else if (EP == 3) {
                    ((float*)outp)[(long)gm * N + gn] = v + bias[gn];
                } else {
                    ((unsigned short*)outp)[(long)gm * N + gn] = f2bf(v);
                }
            }
}

// ---------------- flash attention v4: global_load_lds staging + swizzled layouts ----------------
// Qh, Kh: [bh][2048][64] swizzled; KhTp: [bh][64][2048] perm+swizzled.
// out: [4096][1024] bf16 (col=d*16+h). Streaming softmax (no running max).
template <int USE_MASK>
__global__ __launch_bounds__(256) void flash_attn4_k(const unsigned short* __restrict__ Qh,
                                                     const unsigned short* __restrict__ Kh,
                                                     const unsigned short* __restrict__ KhTp,
                                                     const int* __restrict__ maskp,
                                                     unsigned short* __restrict__ out) {
    __shared__ __align__(16) unsigned short Qs[64 * 64];
    __shared__ __align__(16) unsigned short K1[64 * 64]; // [m][d] swizzled groups
    __shared__ __align__(16) unsigned short K2[64 * 64]; // [d][p] swizzled groups
    __shared__ __align__(16) unsigned short Ps[64 * 72]; // [l][p] padded, plain
    __shared__ float maskf[64];

    int tid = threadIdx.x;
    int wave = tid >> 6, lane = tid & 63;
    int quad = lane >> 4, l16 = lane & 15;
    int bh = blockIdx.y, b = bh >> 4, h = bh & 15;
    int l0 = blockIdx.x * 64;
    const unsigned short* Qsrc = Qh + ((long)bh * 2048 + l0) * 64 + tid * 8;
    const unsigned short* k1p = Kh + (long)bh * 2048 * 64 + tid * 8;
    const unsigned short* k2p = KhTp + (long)bh * 64 * 2048 + (long)(tid >> 3) * 2048 + (tid & 7) * 8;

    __builtin_amdgcn_global_load_lds(GLB(Qsrc), LDS(Qs + tid * 8), 16, 0, 0);
    __builtin_amdgcn_global_load_lds(GLB(Qsrc + 2048), LDS(Qs + tid * 8 + 2048), 16, 0, 0);

    const float C1 = 0.125f * LOG2E;
    f32x4_t acc_o[4] = {};
    float rs[4] = {0.f, 0.f, 0.f, 0.f};

    int sw = l16 & 7;

    for (int m0 = 0; m0 < 2048; m0 += 64) {
        __syncthreads();
        __builtin_amdgcn_global_load_lds(GLB(k1p), LDS(K1 + tid * 8), 16, 0, 0);
        __builtin_amdgcn_global_load_lds(GLB(k1p + 2048), LDS(K1 + tid * 8 + 2048), 16, 0, 0);
        __builtin_amdgcn_global_load_lds(GLB(k2p), LDS(K2 + tid * 8), 16, 0, 0);
        __builtin_amdgcn_global_load_lds(GLB(k2p + 32 * 2048), LDS(K2 + tid * 8 + 2048), 16, 0, 0);
        if (USE_MASK && tid < 64) maskf[tid] = maskp[b * 2048 + m0 + tid] ? -1e10f : 0.0f;
        __syncthreads();

        // S = Q @ Ktile^T : wave handles 16 Q rows (band = wave*16), 64 m cols
        f32x4_t sacc[4] = {};
#pragma unroll
        for (int kk = 0; kk < 2; kk++) {
            int xg = ((kk * 4 + quad) ^ sw) * 8;
            bf16x8_t af = *(const bf16x8_t*)(Qs + (wave * 16 + l16) * 64 + xg);
#pragma unroll
            for (int nt = 0; nt < 4; nt++) {
                bf16x8_t bfr = *(const bf16x8_t*)(K1 + (nt * 16 + l16) * 64 + xg);
                sacc[nt] = __builtin_amdgcn_mfma_f32_16x16x32_bf16(af, bfr, sacc[nt], 0, 0, 0);
            }
        }

        float mf0 = 0.f, mf1 = 0.f, mf2 = 0.f, mf3 = 0.f;
        if (USE_MASK) {
            mf0 = maskf[l16]; mf1 = maskf[16 + l16];
            mf2 = maskf[32 + l16]; mf3 = maskf[48 + l16];
        }

        // p = exp2(s*C1 + mf); per-lane row-sum; write P b64 (4 bf16, permuted cols)
#pragma unroll
        for (int r = 0; r < 4; r++) {
            float p0 = exp2f(fmaf(sacc[0][r], C1, mf0));
            float p1 = exp2f(fmaf(sacc[1][r], C1, mf1));
            float p2 = exp2f(fmaf(sacc[2][r], C1, mf2));
            float p3 = exp2f(fmaf(sacc[3][r], C1, mf3));
            rs[r] += (p0 + p1) + (p2 + p3);
            uint2 pk; pk.x = pack2bf(p0, p1); pk.y = pack2bf(p2, p3);
            *(uint2*)(Ps + (wave * 16 + quad * 4 + r) * 72 + l16 * 4) = pk;
        }

        // O += P @ Ktile : A = own band of Ps (plain), B = K2 (swizzled) — perm-invariant sum
#pragma unroll
        for (int kk = 0; kk < 2; kk++) {
            int xg = ((kk * 4 + quad) ^ sw) * 8;
            bf16x8_t af = *(const bf16x8_t*)(Ps + (wave * 16 + l16) * 72 + kk * 32 + quad * 8);
#pragma unroll
            for (int nt = 0; nt < 4; nt++) {
                bf16x8_t bfr = *(const bf16x8_t*)(K2 + (nt * 16 + l16) * 64 + xg);
                acc_o[nt] = __builtin_amdgcn_mfma_f32_16x16x32_bf16(af, bfr, acc_o[nt], 0, 0, 0);
            }
        }
        k1p += 4096;
        k2p += 64;
    }

    // single final reduction of row sums across the 16 l16 lanes
#pragma unroll
    for (int r = 0; r < 4; r++) {
#pragma unroll
        for (int d = 1; d < 16; d <<= 1) rs[r] += __shfl_xor(rs[r], d);
    }

#pragma unroll
    for (int r = 0; r < 4; r++) {
        float inv = 1.0f / rs[r];
        int l = l0 + wave * 16 + quad * 4 + r;
#pragma unroll
        for (int nt = 0; nt < 4; nt++) {
            int d = nt * 16 + l16;
            out[((long)(b * 2048 + l)) * 1024 + d * 16 + h] = f2bf(acc_o[nt][r] * inv);
        }
    }
}

// ---------------- residual + layernorm: out = LN(a + rb) * g + b ----------------
__global__ __launch_bounds__(256) void resid_ln_k(const float* __restrict__ a,
                                                  const float* __restrict__ rb,
                                                  const float* __restrict__ g,
                                                  const float* __restrict__ bb,
                                                  float* __restrict__ outf,
                                                  unsigned short* __restrict__ outb) {
    long row = blockIdx.x;
    int tid = threadIdx.x;
    float4 va = ((const float4*)(a + row * 1024))[tid];
    float4 vr = ((const float4*)(rb + row * 1024))[tid];
    float x0 = va.x + vr.x, x1 = va.y + vr.y, x2 = va.z + vr.z, x3 = va.w + vr.w;
    float s = x0 + x1 + x2 + x3;
    float sq = x0 * x0 + x1 * x1 + x2 * x2 + x3 * x3;
#pragma unroll
    for (int d = 1; d < 64; d <<= 1) { s += __shfl_xor(s, d); sq += __shfl_xor(sq, d); }
    __shared__ float ss[4], ssq[4];
    int wave = tid >> 6, lane = tid & 63;
    if (lane == 0) { ss[wave] = s; ssq[wave] = sq; }
    __syncthreads();
    s = ss[0] + ss[1] + ss[2] + ss[3];
    sq = ssq[0] + ssq[1] + ssq[2] + ssq[3];
    float mean = s * (1.0f / 1024.0f);
    float var = sq * (1.0f / 1024.0f) - mean * mean;
    float rstd = rsqrtf(var + 1e-5f);
    float4 vg = ((const float4*)g)[tid];
    float4 vb = ((const float4*)bb)[tid];
    float y0 = (x0 - mean) * rstd * vg.x + vb.x;
    float y1 = (x1 - mean) * rstd * vg.y + vb.y;
    float y2 = (x2 - mean) * rstd * vg.z + vb.z;
    float y3 = (x3 - mean) * rstd * vg.w + vb.w;
    float4 o; o.x = y0; o.y = y1; o.z = y2; o.w = y3;
    ((float4*)(outf + row * 1024))[tid] = o;
    ushort4 ob; ob.x = f2bf(y0); ob.y = f2bf(y1); ob.z = f2bf(y2); ob.w = f2bf(y3);
    ((ushort4*)(outb + row * 1024))[tid] = ob;
}

extern "C" void kernel_launch(void* const* d_in, const int* in_sizes, int n_in,
                              void* d_out, int out_size, void* d_ws, size_t ws_size,
                              hipStream_t stream) {
    const float* x    = (const float*)d_in[0];
    const float* enc  = (const float*)d_in[1];
    const int*   mask = (const int*)d_in[2];
    const float* q1W  = (const float*)d_in[3];
    const float* w1W  = (const float*)d_in[4];
    const float* o1W  = (const float*)d_in[5];
    const float* q2W  = (const float*)d_in[6];
    const float* w2W  = (const float*)d_in[7];
    const float* o2W  = (const float*)d_in[8];
    const float* ffW1 = (const float*)d_in[9];
    const float* ffb1 = (const float*)d_in[10];
    const float* ffW2 = (const float*)d_in[11];
    const float* ffb2 = (const float*)d_in[12];
    const float* g1 = (const float*)d_in[13];
    const float* b1 = (const float*)d_in[14];
    const float* g2 = (const float*)d_in[15];
    const float* b2 = (const float*)d_in[16];
    const float* g3 = (const float*)d_in[17];
    const float* b3 = (const float*)d_in[18];
    float* outp = (float*)d_out;

    const int T = 4096;   // B*L
    const int D = 1024;
    const int F = 4096;   // MLP

    char* ws = (char*)d_ws;
    auto alloc = [&](size_t sz) { char* p = ws; ws += (sz + 255) & ~(size_t)255; return p; };
    unsigned short* qw1Wt = (unsigned short*)alloc((size_t)2 * D * D * 2); // fused [2048][1024]
    unsigned short* o1Wt  = (unsigned short*)alloc((size_t)D * D * 2);
    unsigned short* q2Wt  = (unsigned short*)alloc((size_t)D * D * 2);
    unsigned short* w2Wt  = (unsigned short*)alloc((size_t)D * D * 2);
    unsigned short* o2Wt  = (unsigned short*)alloc((size_t)D * D * 2);
    unsigned short* ffW1t = (unsigned short*)alloc((size_t)F * D * 2);
    unsigned short* ffW2t = (unsigned short*)alloc((size_t)D * F * 2);
    unsigned short* xb    = (unsigned short*)alloc((size_t)T * D * 2);
    unsigned short* encb  = (unsigned short*)alloc((size_t)T * D * 2);
    unsigned short* Qhb   = (unsigned short*)alloc((size_t)T * D * 2);
    unsigned short* Khb   = (unsigned short*)alloc((size_t)T * D * 2);
    unsigned short* KhTb  = (unsigned short*)alloc((size_t)T * D * 2);
    unsigned short* attnb = (unsigned short*)alloc((size_t)T * D * 2);
    float*          projf = (float*)alloc((size_t)T * D * 4);
    float*          x1f   = (float*)alloc((size_t)T * D * 4);
    unsigned short* x1b   = (unsigned short*)alloc((size_t)T * D * 2);
    float*          x2f   = (float*)alloc((size_t)T * D * 4);
    unsigned short* x2b   = (unsigned short*)alloc((size_t)T * D * 2);
    unsigned short* S1    = (unsigned short*)alloc((size_t)T * F * 2); // 32 MB scratch
    unsigned short* tmpqw = S1;                 // [4096][2048]
    unsigned short* q2o   = S1;                 // [4096][1024]
    unsigned short* w2o   = S1 + (size_t)T * D; // [4096][1024]
    unsigned short* hb    = S1;                 // [4096][4096]

    dim3 blk256(256);
    dim3 tblk(32, 8);

    // prologue: fused casts + fused weight transposes
    cast2_bf16_k<<<dim3(T * D / 4 / 256, 2), blk256, 0, stream>>>(x, xb, enc, encb, T * D / 4);
    transpose_all_k<<<dim3(14336), tblk, 0, stream>>>(
        q1W, w1W, o1W, q2W, w2W, o2W, ffW1, ffW2,
        qw1Wt, qw1Wt + (size_t)D * D, o1Wt, q2Wt, w2Wt, o2Wt, ffW1t, ffW2t);

    // ---- self attention ----
    gemm_k<4, 128><<<dim3(2 * D / 128, T / 128, 1), blk256, 0, stream>>>(
        xb, qw1Wt, tmpqw, nullptr, nullptr, nullptr, nullptr, T, 2 * D, D);
    split_qk_k<<<dim3(T / 16), blk256, 0, stream>>>(tmpqw, tmpqw, 2 * D, D, Qhb, Khb);
    transpose_heads_perm_k<<<dim3(32, 32), blk256, 0, stream>>>(Khb, KhTb);
    flash_attn4_k<0><<<dim3(32, 32), blk256, 0, stream>>>(Qhb, Khb, KhTb, nullptr, attnb);
    gemm_k<0, 64><<<dim3(D / 64, T / 128, 1), blk256, 0, stream>>>(
        attnb, o1Wt, projf, nullptr, nullptr, nullptr, nullptr, T, D, D);
    resid_ln_k<<<dim3(T), blk256, 0, stream>>>(x, projf, g1, b1, x1f, x1b);

    // ---- cross attention ----
    gemm_k<4, 64><<<dim3(D / 64, T / 128, 2), blk256, 0, stream>>>(
        x1b, q2Wt, q2o, nullptr, encb, w2Wt, w2o, T, D, D);
    split_qk_k<<<dim3(T / 16), blk256, 0, stream>>>(q2o, w2o, D, 0, Qhb, Khb);
    transpose_heads_perm_k<<<dim3(32, 32), blk256, 0, stream>>>(Khb, KhTb);
    flash_attn4_k<1><<<dim3(32, 32), blk256, 0, stream>>>(Qhb, Khb, KhTb, mask, attnb);
    gemm_k<0, 64><<<dim3(D / 64, T / 128, 1), blk256, 0, stream>>>(
        attnb, o2Wt, projf, nullptr, nullptr, nullptr, nullptr, T, D, D);
    resid_ln_k<<<dim3(T), blk256, 0, stream>>>(x1f, projf, g2, b2, x2f, x2b);

    // ---- feed forward ----
    gemm_k<2, 128><<<dim3(F / 128, T / 128, 1), blk256, 0, stream>>>(
        x2b, ffW1t, hb, ffb1, nullptr, nullptr, nullptr, T, F, D);
    gemm_k<3, 64><<<dim3(D / 64, T / 128, 1), blk256, 0, stream>>>(
        hb, ffW2t, projf, ffb2, nullptr, nullptr, nullptr, T, D, F);
    resid_ln_k<<<dim3(T), blk256, 0, stream>>>(x2f, projf, g3, b3, outp, x2b);
}